// Round 9
// baseline (162.006 us; speedup 1.0000x reference)
//
#include <hip/hip_runtime.h>
#include <hip/hip_bf16.h>

#define BB   2
#define NNN  2048
#define DIN  256
#define HH   8
#define DHD  32
#define NW   32   // u64 mask words per row (8 groups x 4 ballot words)

typedef __attribute__((ext_vector_type(8))) short short8;
typedef __attribute__((ext_vector_type(4))) float f32x4;
typedef __attribute__((ext_vector_type(16))) float f32x16;

#if __has_builtin(__builtin_amdgcn_exp2f)
#define EXP2(x) __builtin_amdgcn_exp2f(x)
#else
#define EXP2(x) exp2f(x)
#endif

__device__ __forceinline__ unsigned int pk2(float a, float b) {
  union { __hip_bfloat162 h2; unsigned int u; } cv;
  cv.h2 = __float22bfloat162_rn(float2{a, b});   // v_cvt_pk_bf16_f32, RNE
  return cv.u;
}
__device__ __forceinline__ unsigned short f2bf(float f) {
  unsigned int u = __float_as_uint(f);
  u += 0x7fffu + ((u >> 16) & 1u);
  return (unsigned short)(u >> 16);
}

#define QSCALE (0.17677669529663687f * 1.4426950408889634f)  // 1/sqrt(32) * log2(e)

// ---------------- K0: adj -> ballot masks  +  Wo cast ----------------
__global__ __launch_bounds__(256) void build_mask(
    const float* __restrict__ adj, unsigned long long* __restrict__ Mk,
    const float* __restrict__ Wo, unsigned short* __restrict__ Wob) {
  const int bid = blockIdx.x, tid = threadIdx.x;
  if (bid < 1024) {
    const int lane = tid & 63;
    const int row = bid * 4 + (tid >> 6);
    const float* rp = adj + (size_t)row * NNN + lane * 4;
    #pragma unroll
    for (int o = 0; o < 2; ++o) {
      float4 vv[4];
      #pragma unroll
      for (int g = 0; g < 4; ++g)
        vv[g] = *(const float4*)(rp + (o * 4 + g) * 256);
      #pragma unroll
      for (int g = 0; g < 4; ++g) {
        unsigned long long b0 = __ballot(vv[g].x != 0.0f);
        unsigned long long b1 = __ballot(vv[g].y != 0.0f);
        unsigned long long b2 = __ballot(vv[g].z != 0.0f);
        unsigned long long b3 = __ballot(vv[g].w != 0.0f);
        if (lane < 4) {
          unsigned long long bs = (lane == 0) ? b0 : (lane == 1) ? b1 : (lane == 2) ? b2 : b3;
          Mk[(size_t)row * NW + (o * 4 + g) * 4 + lane] = bs;
        }
      }
    }
  } else {
    int i = (bid - 1024) * 1024 + tid * 4;
    float4 v = *(const float4*)(Wo + i);
    unsigned int p[2] = {pk2(v.x, v.y), pk2(v.z, v.w)};
    *(uint2*)(Wob + i) = *(const uint2*)p;
  }
}

// ---------------- K1: QKV projection, W staged in LDS ----------------
__global__ __launch_bounds__(256) void qkv_gemm(
    const float* __restrict__ x, const float* __restrict__ Wq,
    const float* __restrict__ Wk, const float* __restrict__ Wv,
    unsigned short* __restrict__ Qb, unsigned short* __restrict__ Kb,
    unsigned short* __restrict__ Vt) {
  __shared__ __align__(16) unsigned short Wl[64][264];
  const int tid = threadIdx.x;
  const int y = blockIdx.x >> 6, rb = blockIdx.x & 63;
  const int mat = y >> 2, ocb = (y & 3) * 64;
  const float* Wsrc = ((mat == 0) ? Wq : (mat == 1) ? Wk : Wv) + (size_t)ocb * DIN;

  #pragma unroll
  for (int it = 0; it < 16; ++it) {
    int f4 = it * 256 + tid;
    int oc = f4 >> 6, k4 = f4 & 63;
    float4 v = *(const float4*)(Wsrc + (size_t)oc * DIN + k4 * 4);
    unsigned int p[2] = {pk2(v.x, v.y), pk2(v.z, v.w)};
    *(uint2*)&Wl[oc][k4 * 4] = *(const uint2*)p;
  }
  __syncthreads();

  const int w = tid >> 6, lane = tid & 63, col = lane & 15, quad = lane >> 4;
  const int row0 = rb * 64 + w * 16;

  f32x4 acc[4];
  #pragma unroll
  for (int c = 0; c < 4; ++c) acc[c] = (f32x4){0.f, 0.f, 0.f, 0.f};

  #pragma unroll
  for (int kk = 0; kk < 8; ++kk) {
    const float* xp = x + (size_t)(row0 + col) * DIN + kk * 32 + quad * 8;
    float4 a0 = *(const float4*)xp, a1 = *(const float4*)(xp + 4);
    union { short8 s; unsigned int u[4]; } af;
    af.u[0] = pk2(a0.x, a0.y); af.u[1] = pk2(a0.z, a0.w);
    af.u[2] = pk2(a1.x, a1.y); af.u[3] = pk2(a1.z, a1.w);
    #pragma unroll
    for (int c = 0; c < 4; ++c) {
      short8 bw = *(const short8*)&Wl[c * 16 + col][kk * 32 + quad * 8];
      acc[c] = __builtin_amdgcn_mfma_f32_16x16x32_bf16(af.s, bw, acc[c], 0, 0, 0);
    }
  }
  const float scale = (mat == 0) ? QSCALE : 1.0f;
  #pragma unroll
  for (int c = 0; c < 4; ++c) {
    int oc = ocb + c * 16 + col, h = oc >> 5, dh = oc & 31;
    #pragma unroll
    for (int r = 0; r < 4; ++r) {
      int row = row0 + quad * 4 + r;
      int b = row >> 11, n = row & (NNN - 1);
      unsigned short val = f2bf(acc[c][r] * scale);
      if (mat == 2)       Vt[((size_t)(b * HH + h) * DHD + dh) * NNN + n] = val;
      else if (mat == 0)  Qb[((size_t)(b * HH + h) * NNN + n) * DHD + dh] = val;
      else                Kb[((size_t)(b * HH + h) * NNN + n) * DHD + dh] = val;
    }
  }
}

// ---------------- K2: fused masked attention, 2 q-tiles per wave ----------------
// 512 blocks x 512 thr (8 waves). Wave w: keys [w*256,(w+1)*256) for 64 queries
// (2 tiles of 32): K/V sub-tile loaded ONCE, used for both tiles (halves L2 traffic).
// XCD-swizzled; no-max softmax; ballot masks; P via shfl; 2-pass LDS combine.
__global__ __launch_bounds__(512, 4) void attn(
    const unsigned short* __restrict__ Qb, const unsigned short* __restrict__ Kb,
    const unsigned short* __restrict__ Vt, const unsigned long long* __restrict__ Mk,
    unsigned short* __restrict__ AOb) {
  __shared__ float OL[8][32][33];
  __shared__ float LL[8][32];
  const int tid = threadIdx.x;
  const int w = tid >> 6, lane = tid & 63;
  const int qi = lane & 31, hi = lane >> 5;
  const int bid = blockIdx.x;
  const int xcd = bid & 7, j = bid >> 3;      // j in [0,64)
  const int bh = xcd * 2 + (j >> 5);          // 2 bh per XCD
  const int qg = j & 31;                      // 64-query group
  const int b = bh >> 3, h = bh & 7;
  const int q0 = qg * 64 + qi;                // tile 0 query; tile 1 = q0+32
  const int k0 = w * 256;

  short8 bq[2][2];
  {
    const unsigned short* qp0 = Qb + ((size_t)bh * NNN + q0) * DHD + hi * 8;
    bq[0][0] = *(const short8*)qp0;
    bq[0][1] = *(const short8*)(qp0 + 16);
    const unsigned short* qp1 = qp0 + 32 * DHD;
    bq[1][0] = *(const short8*)qp1;
    bq[1][1] = *(const short8*)(qp1 + 16);
  }

  f32x16 accO[2];
  float lsum[2] = {0.f, 0.f};
  #pragma unroll
  for (int tt = 0; tt < 2; ++tt)
    #pragma unroll
    for (int i = 0; i < 16; ++i) accO[tt][i] = 0.f;

  unsigned long long bm[2][4];
  {
    const unsigned long long* mrow0 = Mk + ((size_t)b * NNN + q0) * NW + w * 4;
    const unsigned long long* mrow1 = mrow0 + (size_t)32 * NW;
    #pragma unroll
    for (int c = 0; c < 4; ++c) { bm[0][c] = mrow0[c]; bm[1][c] = mrow1[c]; }
  }

  const unsigned short* kbase = Kb + ((size_t)bh * NNN + k0 + qi) * DHD + hi * 8;  // qi = key
  const unsigned short* vbase = Vt + ((size_t)bh * DHD + qi) * NNN + k0 + hi * 8;  // qi = dh

  #pragma unroll 2
  for (int sub = 0; sub < 8; ++sub) {
    const int kb = sub * 32;
    short8 ak0 = *(const short8*)(kbase + (size_t)kb * DHD);
    short8 ak1 = *(const short8*)(kbase + (size_t)kb * DHD + 16);
    short8 av0 = *(const short8*)(vbase + kb);
    short8 av1 = *(const short8*)(vbase + kb + 16);

    #pragma unroll
    for (int tt = 0; tt < 2; ++tt) {
      unsigned int mb[4];
      #pragma unroll
      for (int c = 0; c < 4; ++c) mb[c] = (unsigned int)(bm[tt][c] >> (sub * 8)) & 0xffu;

      f32x16 z;
      #pragma unroll
      for (int i = 0; i < 16; ++i) z[i] = 0.f;
      // S^T: A=K(m=key), B=Q(n=query); C: query=lane&31, key=(reg&3)+8*(reg>>2)+4*hi
      f32x16 st = __builtin_amdgcn_mfma_f32_32x32x16_bf16(ak0, bq[tt][0], z, 0, 0, 0);
      st = __builtin_amdgcn_mfma_f32_32x32x16_bf16(ak1, bq[tt][1], st, 0, 0, 0);

      unsigned int pk[4][2];
      #pragma unroll
      for (int g = 0; g < 4; ++g) {
        float pv[4];
        #pragma unroll
        for (int r = 0; r < 4; ++r) {
          float e = EXP2(st[g * 4 + r]);
          int msk = ((int)(mb[r] << (31 - (g * 2 + hi)))) >> 31;
          float p = __uint_as_float(__float_as_uint(e) & (unsigned int)msk);
          pv[r] = p;
          lsum[tt] += p;
        }
        pk[g][0] = pk2(pv[0], pv[1]);
        pk[g][1] = pk2(pv[2], pv[3]);
      }

      // cross-lane exchange: lane needs partner(hi^1)'s group g=hi (frag1) / 2+hi (frag2)
      unsigned int kA0 = hi ? pk[1][0] : pk[0][0], kA1 = hi ? pk[1][1] : pk[0][1];
      unsigned int tA0 = hi ? pk[0][0] : pk[1][0], tA1 = hi ? pk[0][1] : pk[1][1];
      unsigned int kB0 = hi ? pk[3][0] : pk[2][0], kB1 = hi ? pk[3][1] : pk[2][1];
      unsigned int tB0 = hi ? pk[2][0] : pk[3][0], tB1 = hi ? pk[2][1] : pk[3][1];
      unsigned int xA0 = __shfl_xor((int)tA0, 32, 64), xA1 = __shfl_xor((int)tA1, 32, 64);
      unsigned int xB0 = __shfl_xor((int)tB0, 32, 64), xB1 = __shfl_xor((int)tB1, 32, 64);

      union { short8 s; unsigned int u[4]; } F1, F2;
      F1.u[0] = hi ? xA0 : kA0; F1.u[1] = hi ? xA1 : kA1;
      F1.u[2] = hi ? kA0 : xA0; F1.u[3] = hi ? kA1 : xA1;
      F2.u[0] = hi ? xB0 : kB0; F2.u[1] = hi ? xB1 : kB1;
      F2.u[2] = hi ? kB0 : xB0; F2.u[3] = hi ? kB1 : xB1;

      // O^T += V^T * P^T
      accO[tt] = __builtin_amdgcn_mfma_f32_32x32x16_bf16(av0, F1.s, accO[tt], 0, 0, 0);
      accO[tt] = __builtin_amdgcn_mfma_f32_32x32x16_bf16(av1, F2.s, accO[tt], 0, 0, 0);
    }
  }

  lsum[0] += __shfl_xor(lsum[0], 32, 64);   // hi halves cover disjoint keys
  lsum[1] += __shfl_xor(lsum[1], 32, 64);

  // two-pass combine (LDS holds one 32-q tile at a time)
  #pragma unroll
  for (int tt = 0; tt < 2; ++tt) {
    #pragma unroll
    for (int g = 0; g < 4; ++g)
      #pragma unroll
      for (int r = 0; r < 4; ++r)
        OL[w][qi][g * 8 + hi * 4 + r] = accO[tt][g * 4 + r];
    if (hi == 0) LL[w][qi] = lsum[tt];
    __syncthreads();

    const int ql = tid >> 4, c2 = (tid & 15) * 2;
    float l = 0.f, o0 = 0.f, o1 = 0.f;
    #pragma unroll
    for (int ww = 0; ww < 8; ++ww) {
      l  += LL[ww][ql];
      o0 += OL[ww][ql][c2];
      o1 += OL[ww][ql][c2 + 1];
    }
    float inv = 1.0f / l;
    unsigned int pr = pk2(o0 * inv, o1 * inv);
    *(unsigned int*)(AOb + ((size_t)(b * NNN + qg * 64 + tt * 32 + ql)) * DIN + h * DHD + c2) = pr;
    __syncthreads();
  }
}

// ---------------- K3: output projection + bias via bf16 MFMA ----------------
__global__ __launch_bounds__(256) void out_proj(const unsigned short* __restrict__ AOb,
                                                const unsigned short* __restrict__ Wob,
                                                const float* __restrict__ bo,
                                                float* __restrict__ out) {
  const int tid = threadIdx.x;
  const int lane = tid & 63, col = lane & 15, quad = lane >> 4;
  const int task = blockIdx.x * 4 + (tid >> 6);    // 1024 tasks
  const int row0 = (task >> 2) * 16;
  const int ocb = (task & 3) * 64;

  f32x4 acc[4];
  #pragma unroll
  for (int c = 0; c < 4; ++c) acc[c] = (f32x4){0.f, 0.f, 0.f, 0.f};

  #pragma unroll
  for (int kk = 0; kk < 8; ++kk) {
    short8 af = *(const short8*)(AOb + (size_t)(row0 + col) * DIN + kk * 32 + quad * 8);
    #pragma unroll
    for (int c = 0; c < 4; ++c) {
      short8 bw = *(const short8*)(Wob + (size_t)(ocb + c * 16 + col) * DIN + kk * 32 + quad * 8);
      acc[c] = __builtin_amdgcn_mfma_f32_16x16x32_bf16(af, bw, acc[c], 0, 0, 0);
    }
  }
  #pragma unroll
  for (int c = 0; c < 4; ++c) {
    int oc = ocb + c * 16 + col;
    float bias = bo[oc];
    #pragma unroll
    for (int r = 0; r < 4; ++r)
      out[(size_t)(row0 + quad * 4 + r) * DIN + oc] = acc[c][r] + bias;
  }
}

extern "C" void kernel_launch(void* const* d_in, const int* in_sizes, int n_in,
                              void* d_out, int out_size, void* d_ws, size_t ws_size,
                              hipStream_t stream) {
  const float* x   = (const float*)d_in[0];
  const float* adj = (const float*)d_in[1];
  const float* Wq  = (const float*)d_in[2];
  const float* Wk  = (const float*)d_in[3];
  const float* Wv  = (const float*)d_in[4];
  const float* Wo  = (const float*)d_in[5];
  const float* bo  = (const float*)d_in[6];
  float* out = (float*)d_out;

  char* ws = (char*)d_ws;
  unsigned short* Qb  = (unsigned short*)(ws);                         // 2 MB
  unsigned short* Kb  = (unsigned short*)(ws + (2ull << 20));          // 2 MB
  unsigned short* Vt  = (unsigned short*)(ws + (4ull << 20));          // 2 MB
  unsigned long long* Mk = (unsigned long long*)(ws + (6ull << 20));   // 1 MB
  unsigned short* Wob = (unsigned short*)(ws + (7ull << 20));          // 128 KB
  unsigned short* AOb = (unsigned short*)(ws + (8ull << 20));          // 2 MB

  build_mask<<<dim3(1088), 256, 0, stream>>>(adj, Mk, Wo, Wob);
  qkv_gemm<<<dim3(768), 256, 0, stream>>>(x, Wq, Wk, Wv, Qb, Kb, Vt);
  attn<<<dim3(512), 512, 0, stream>>>(Qb, Kb, Vt, Mk, AOb);
  out_proj<<<dim3(256), 256, 0, stream>>>(AOb, Wob, bo, out);
}

// Round 10
// 139.740 us; speedup vs baseline: 1.1593x; 1.1593x over previous
//
#include <hip/hip_runtime.h>
#include <hip/hip_bf16.h>

#define BB   2
#define NNN  2048
#define DIN  256
#define HH   8
#define DHD  32
#define NW   32   // u64 mask words per row (8 groups x 4 ballot words)

typedef __attribute__((ext_vector_type(8))) short short8;
typedef __attribute__((ext_vector_type(4))) float f32x4;
typedef __attribute__((ext_vector_type(16))) float f32x16;

#if __has_builtin(__builtin_amdgcn_exp2f)
#define EXP2(x) __builtin_amdgcn_exp2f(x)
#else
#define EXP2(x) exp2f(x)
#endif

__device__ __forceinline__ unsigned int pk2(float a, float b) {
  union { __hip_bfloat162 h2; unsigned int u; } cv;
  cv.h2 = __float22bfloat162_rn(float2{a, b});   // v_cvt_pk_bf16_f32, RNE
  return cv.u;
}
__device__ __forceinline__ unsigned short f2bf(float f) {
  unsigned int u = __float_as_uint(f);
  u += 0x7fffu + ((u >> 16) & 1u);
  return (unsigned short)(u >> 16);
}

#define QSCALE (0.17677669529663687f * 1.4426950408889634f)  // 1/sqrt(32) * log2(e)

// ---------------- K0 prep: masks + Wo cast + QKV gemm (disjoint block ranges) ----------------
// [0,1024): adj -> ballot masks, 1 wave = 1 row
// [1024,1088): Wo fp32 -> bf16
// [1088,2624): QKV MFMA gemm, 32-out-col tiles, W staged in LDS (16.9 KB -> 8 blocks/CU)
__global__ __launch_bounds__(256) void prep(
    const float* __restrict__ adj, unsigned long long* __restrict__ Mk,
    const float* __restrict__ x, const float* __restrict__ Wq,
    const float* __restrict__ Wk, const float* __restrict__ Wv,
    unsigned short* __restrict__ Qb, unsigned short* __restrict__ Kb,
    unsigned short* __restrict__ Vt,
    const float* __restrict__ Wo, unsigned short* __restrict__ Wob) {
  __shared__ __align__(16) unsigned short Wl[32][264];   // 16.9 KB
  const int bid = blockIdx.x, tid = threadIdx.x;
  const int w = tid >> 6, lane = tid & 63;

  if (bid < 1024) {                       // ---- masks ----
    const int row = bid * 4 + w;
    const float* rp = adj + (size_t)row * NNN + lane * 4;
    #pragma unroll
    for (int o = 0; o < 2; ++o) {
      float4 vv[4];
      #pragma unroll
      for (int g = 0; g < 4; ++g)
        vv[g] = *(const float4*)(rp + (o * 4 + g) * 256);
      #pragma unroll
      for (int g = 0; g < 4; ++g) {
        unsigned long long b0 = __ballot(vv[g].x != 0.0f);
        unsigned long long b1 = __ballot(vv[g].y != 0.0f);
        unsigned long long b2 = __ballot(vv[g].z != 0.0f);
        unsigned long long b3 = __ballot(vv[g].w != 0.0f);
        if (lane < 4) {
          unsigned long long bs = (lane == 0) ? b0 : (lane == 1) ? b1 : (lane == 2) ? b2 : b3;
          Mk[(size_t)row * NW + (o * 4 + g) * 4 + lane] = bs;
        }
      }
    }
  } else if (bid < 1088) {                // ---- Wo cast ----
    int i = (bid - 1024) * 1024 + tid * 4;
    float4 v = *(const float4*)(Wo + i);
    unsigned int p[2] = {pk2(v.x, v.y), pk2(v.z, v.w)};
    *(uint2*)(Wob + i) = *(const uint2*)p;
  } else {                                // ---- QKV gemm ----
    const int t = bid - 1088;             // 0..1535
    const int y = t >> 6, rb = t & 63;
    const int mat = y >> 3, ocb = (y & 7) * 32;
    const float* Wsrc = ((mat == 0) ? Wq : (mat == 1) ? Wk : Wv) + (size_t)ocb * DIN;

    #pragma unroll
    for (int it = 0; it < 8; ++it) {
      int f4 = it * 256 + tid;
      int oc = f4 >> 6, k4 = f4 & 63;
      float4 v = *(const float4*)(Wsrc + (size_t)oc * DIN + k4 * 4);
      unsigned int p[2] = {pk2(v.x, v.y), pk2(v.z, v.w)};
      *(uint2*)&Wl[oc][k4 * 4] = *(const uint2*)p;
    }
    __syncthreads();

    const int col = lane & 15, quad = lane >> 4;
    const int row0 = rb * 64 + w * 16;

    f32x4 acc[2];
    #pragma unroll
    for (int c = 0; c < 2; ++c) acc[c] = (f32x4){0.f, 0.f, 0.f, 0.f};

    #pragma unroll
    for (int kk = 0; kk < 8; ++kk) {
      const float* xp = x + (size_t)(row0 + col) * DIN + kk * 32 + quad * 8;
      float4 a0 = *(const float4*)xp, a1 = *(const float4*)(xp + 4);
      union { short8 s; unsigned int u[4]; } af;
      af.u[0] = pk2(a0.x, a0.y); af.u[1] = pk2(a0.z, a0.w);
      af.u[2] = pk2(a1.x, a1.y); af.u[3] = pk2(a1.z, a1.w);
      #pragma unroll
      for (int c = 0; c < 2; ++c) {
        short8 bw = *(const short8*)&Wl[c * 16 + col][kk * 32 + quad * 8];
        acc[c] = __builtin_amdgcn_mfma_f32_16x16x32_bf16(af.s, bw, acc[c], 0, 0, 0);
      }
    }
    const float scale = (mat == 0) ? QSCALE : 1.0f;
    #pragma unroll
    for (int c = 0; c < 2; ++c) {
      int oc = ocb + c * 16 + col, h = oc >> 5, dh = oc & 31;
      #pragma unroll
      for (int r = 0; r < 4; ++r) {
        int row = row0 + quad * 4 + r;
        int b = row >> 11, n = row & (NNN - 1);
        unsigned short val = f2bf(acc[c][r] * scale);
        if (mat == 2)       Vt[((size_t)(b * HH + h) * DHD + dh) * NNN + n] = val;
        else if (mat == 0)  Qb[((size_t)(b * HH + h) * NNN + n) * DHD + dh] = val;
        else                Kb[((size_t)(b * HH + h) * NNN + n) * DHD + dh] = val;
      }
    }
  }
}

// ---------------- K1: fused masked attention (R7 structure + VALU diet) ----------------
// 1024 blocks x 512 thr (8 waves); wave w: keys [w*256,(w+1)*256) for 32 queries.
// XCD-swizzled; no-max softmax; hoisted hi-preshift masks (compile-time bit extract);
// 8-shfl cross-lane P exchange; block-end LDS combine -> normalized bf16 AO.
__global__ __launch_bounds__(512, 6) void attn(
    const unsigned short* __restrict__ Qb, const unsigned short* __restrict__ Kb,
    const unsigned short* __restrict__ Vt, const unsigned long long* __restrict__ Mk,
    unsigned short* __restrict__ AOb) {
  __shared__ float OL[8][32][33];
  __shared__ float LL[8][32];
  const int tid = threadIdx.x;
  const int w = tid >> 6, lane = tid & 63;
  const int qi = lane & 31, hi = lane >> 5;
  const int bid = blockIdx.x;
  const int xcd = bid & 7, j = bid >> 3;
  const int bh = xcd * 2 + (j >> 6);       // 2 bh per XCD
  const int qt = j & 63;
  const int b = bh >> 3, h = bh & 7;
  const int q = qt * 32 + qi;
  const int k0 = w * 256;

  const unsigned short* qp = Qb + ((size_t)bh * NNN + q) * DHD + hi * 8;
  const short8 bq0 = *(const short8*)qp;
  const short8 bq1 = *(const short8*)(qp + 16);

  f32x16 accO;
  #pragma unroll
  for (int i = 0; i < 16; ++i) accO[i] = 0.f;
  float lsum = 0.f;

  // load 4 mask words, pre-shift by hi so every later bit position is compile-time
  const unsigned long long* mrow = Mk + ((size_t)b * NNN + q) * NW + w * 4;
  unsigned int mlo[4], mhi2[4];
  #pragma unroll
  for (int c = 0; c < 4; ++c) {
    unsigned long long mh = mrow[c] >> hi;
    mlo[c]  = (unsigned int)mh;
    mhi2[c] = (unsigned int)(mh >> 32);
  }

  const unsigned short* kbase = Kb + ((size_t)bh * NNN + k0 + qi) * DHD + hi * 8;  // qi = key
  const unsigned short* vbase = Vt + ((size_t)bh * DHD + qi) * NNN + k0 + hi * 8;  // qi = dh

  #pragma unroll
  for (int sub = 0; sub < 8; ++sub) {
    const int kb = sub * 32;

    short8 ak0 = *(const short8*)(kbase + (size_t)kb * DHD);
    short8 ak1 = *(const short8*)(kbase + (size_t)kb * DHD + 16);
    short8 av0 = *(const short8*)(vbase + kb);
    short8 av1 = *(const short8*)(vbase + kb + 16);

    f32x16 z;
    #pragma unroll
    for (int i = 0; i < 16; ++i) z[i] = 0.f;
    // S^T: A=K(m=key), B=Q(n=query); C: query=lane&31, key=(reg&3)+8*(reg>>2)+4*hi
    f32x16 st = __builtin_amdgcn_mfma_f32_32x32x16_bf16(ak0, bq0, z, 0, 0, 0);
    st = __builtin_amdgcn_mfma_f32_32x32x16_bf16(ak1, bq1, st, 0, 0, 0);

    unsigned int pk[4][2];
    #pragma unroll
    for (int g = 0; g < 4; ++g) {
      float pv[4];
      #pragma unroll
      for (int r = 0; r < 4; ++r) {
        // valid bit (pre-shifted): bit ((sub&3)*8 + g*2) of (sub<4 ? mlo[r] : mhi2[r])
        unsigned int mwd = (sub < 4) ? mlo[r] : mhi2[r];
        const int pos = (sub & 3) * 8 + g * 2;          // compile-time (full unroll)
        int msk = ((int)(mwd << (31 - pos))) >> 31;     // folds to v_bfe_i32
        float e = EXP2(st[g * 4 + r]);
        float p = __uint_as_float(__float_as_uint(e) & (unsigned int)msk);
        pv[r] = p;
        lsum += p;
      }
      pk[g][0] = pk2(pv[0], pv[1]);
      pk[g][1] = pk2(pv[2], pv[3]);
    }

    // 8-shfl exchange (no pre-selects): xg* = partner's pk[g][*]
    unsigned int x00 = __shfl_xor((int)pk[0][0], 32, 64), x01 = __shfl_xor((int)pk[0][1], 32, 64);
    unsigned int x10 = __shfl_xor((int)pk[1][0], 32, 64), x11 = __shfl_xor((int)pk[1][1], 32, 64);
    unsigned int x20 = __shfl_xor((int)pk[2][0], 32, 64), x21 = __shfl_xor((int)pk[2][1], 32, 64);
    unsigned int x30 = __shfl_xor((int)pk[3][0], 32, 64), x31 = __shfl_xor((int)pk[3][1], 32, 64);

    union { short8 s; unsigned int u[4]; } F1, F2;
    F1.u[0] = hi ? x10 : pk[0][0];
    F1.u[1] = hi ? x11 : pk[0][1];
    F1.u[2] = hi ? pk[1][0] : x00;
    F1.u[3] = hi ? pk[1][1] : x01;
    F2.u[0] = hi ? x30 : pk[2][0];
    F2.u[1] = hi ? x31 : pk[2][1];
    F2.u[2] = hi ? pk[3][0] : x20;
    F2.u[3] = hi ? pk[3][1] : x21;

    // O^T += V^T * P^T
    accO = __builtin_amdgcn_mfma_f32_32x32x16_bf16(av0, F1.s, accO, 0, 0, 0);
    accO = __builtin_amdgcn_mfma_f32_32x32x16_bf16(av1, F2.s, accO, 0, 0, 0);
  }

  lsum += __shfl_xor(lsum, 32, 64);   // hi halves cover disjoint keys

  #pragma unroll
  for (int g = 0; g < 4; ++g)
    #pragma unroll
    for (int r = 0; r < 4; ++r)
      OL[w][qi][g * 8 + hi * 4 + r] = accO[g * 4 + r];
  if (hi == 0) LL[w][qi] = lsum;
  __syncthreads();

  // 512 threads: 16 threads per query, 2 dh each
  const int ql = tid >> 4, c2 = (tid & 15) * 2;
  float l = 0.f, o0 = 0.f, o1 = 0.f;
  #pragma unroll
  for (int ww = 0; ww < 8; ++ww) {
    l  += LL[ww][ql];
    o0 += OL[ww][ql][c2];
    o1 += OL[ww][ql][c2 + 1];
  }
  float inv = 1.0f / l;
  unsigned int pr = pk2(o0 * inv, o1 * inv);
  *(unsigned int*)(AOb + ((size_t)(b * NNN + qt * 32 + ql)) * DIN + h * DHD + c2) = pr;
}

// ---------------- K2: output projection + bias via bf16 MFMA ----------------
__global__ __launch_bounds__(256) void out_proj(const unsigned short* __restrict__ AOb,
                                                const unsigned short* __restrict__ Wob,
                                                const float* __restrict__ bo,
                                                float* __restrict__ out) {
  const int tid = threadIdx.x;
  const int lane = tid & 63, col = lane & 15, quad = lane >> 4;
  const int task = blockIdx.x * 4 + (tid >> 6);    // 1024 tasks
  const int row0 = (task >> 2) * 16;
  const int ocb = (task & 3) * 64;

  f32x4 acc[4];
  #pragma unroll
  for (int c = 0; c < 4; ++c) acc[c] = (f32x4){0.f, 0.f, 0.f, 0.f};

  #pragma unroll
  for (int kk = 0; kk < 8; ++kk) {
    short8 af = *(const short8*)(AOb + (size_t)(row0 + col) * DIN + kk * 32 + quad * 8);
    #pragma unroll
    for (int c = 0; c < 4; ++c) {
      short8 bw = *(const short8*)(Wob + (size_t)(ocb + c * 16 + col) * DIN + kk * 32 + quad * 8);
      acc[c] = __builtin_amdgcn_mfma_f32_16x16x32_bf16(af, bw, acc[c], 0, 0, 0);
    }
  }
  #pragma unroll
  for (int c = 0; c < 4; ++c) {
    int oc = ocb + c * 16 + col;
    float bias = bo[oc];
    #pragma unroll
    for (int r = 0; r < 4; ++r)
      out[(size_t)(row0 + quad * 4 + r) * DIN + oc] = acc[c][r] + bias;
  }
}

extern "C" void kernel_launch(void* const* d_in, const int* in_sizes, int n_in,
                              void* d_out, int out_size, void* d_ws, size_t ws_size,
                              hipStream_t stream) {
  const float* x   = (const float*)d_in[0];
  const float* adj = (const float*)d_in[1];
  const float* Wq  = (const float*)d_in[2];
  const float* Wk  = (const float*)d_in[3];
  const float* Wv  = (const float*)d_in[4];
  const float* Wo  = (const float*)d_in[5];
  const float* bo  = (const float*)d_in[6];
  float* out = (float*)d_out;

  char* ws = (char*)d_ws;
  unsigned short* Qb  = (unsigned short*)(ws);                         // 2 MB
  unsigned short* Kb  = (unsigned short*)(ws + (2ull << 20));          // 2 MB
  unsigned short* Vt  = (unsigned short*)(ws + (4ull << 20));          // 2 MB
  unsigned long long* Mk = (unsigned long long*)(ws + (6ull << 20));   // 1 MB
  unsigned short* Wob = (unsigned short*)(ws + (7ull << 20));          // 128 KB
  unsigned short* AOb = (unsigned short*)(ws + (8ull << 20));          // 2 MB

  prep<<<dim3(2624), 256, 0, stream>>>(adj, Mk, x, Wq, Wk, Wv, Qb, Kb, Vt, Wo, Wob);
  attn<<<dim3(1024), 512, 0, stream>>>(Qb, Kb, Vt, Mk, AOb);
  out_proj<<<dim3(256), 256, 0, stream>>>(AOb, Wob, bo, out);
}

// Round 11
// 139.727 us; speedup vs baseline: 1.1594x; 1.0001x over previous
//
#include <hip/hip_runtime.h>
#include <hip/hip_bf16.h>

#define BB   2
#define NNN  2048
#define DIN  256
#define HH   8
#define DHD  32
#define NW   32   // u64 mask words per row (8 groups x 4 ballot words)

typedef __attribute__((ext_vector_type(8))) short short8;
typedef __attribute__((ext_vector_type(4))) float f32x4;
typedef __attribute__((ext_vector_type(16))) float f32x16;

#if __has_builtin(__builtin_amdgcn_exp2f)
#define EXP2(x) __builtin_amdgcn_exp2f(x)
#else
#define EXP2(x) exp2f(x)
#endif

__device__ __forceinline__ unsigned int pk2(float a, float b) {
  union { __hip_bfloat162 h2; unsigned int u; } cv;
  cv.h2 = __float22bfloat162_rn(float2{a, b});   // v_cvt_pk_bf16_f32, RNE
  return cv.u;
}
__device__ __forceinline__ unsigned short f2bf(float f) {
  unsigned int u = __float_as_uint(f);
  u += 0x7fffu + ((u >> 16) & 1u);
  return (unsigned short)(u >> 16);
}

#define QSCALE (0.17677669529663687f * 1.4426950408889634f)  // 1/sqrt(32) * log2(e)

// ---------------- K0 prep: masks + Wo cast + QKV gemm (disjoint block ranges) ----------------
__global__ __launch_bounds__(256) void prep(
    const float* __restrict__ adj, unsigned long long* __restrict__ Mk,
    const float* __restrict__ x, const float* __restrict__ Wq,
    const float* __restrict__ Wk, const float* __restrict__ Wv,
    unsigned short* __restrict__ Qb, unsigned short* __restrict__ Kb,
    unsigned short* __restrict__ Vt,
    const float* __restrict__ Wo, unsigned short* __restrict__ Wob) {
  __shared__ __align__(16) unsigned short Wl[32][264];   // 16.9 KB
  const int bid = blockIdx.x, tid = threadIdx.x;
  const int w = tid >> 6, lane = tid & 63;

  if (bid < 1024) {                       // ---- masks ----
    const int row = bid * 4 + w;
    const float* rp = adj + (size_t)row * NNN + lane * 4;
    #pragma unroll
    for (int o = 0; o < 2; ++o) {
      float4 vv[4];
      #pragma unroll
      for (int g = 0; g < 4; ++g)
        vv[g] = *(const float4*)(rp + (o * 4 + g) * 256);
      #pragma unroll
      for (int g = 0; g < 4; ++g) {
        unsigned long long b0 = __ballot(vv[g].x != 0.0f);
        unsigned long long b1 = __ballot(vv[g].y != 0.0f);
        unsigned long long b2 = __ballot(vv[g].z != 0.0f);
        unsigned long long b3 = __ballot(vv[g].w != 0.0f);
        if (lane < 4) {
          unsigned long long bs = (lane == 0) ? b0 : (lane == 1) ? b1 : (lane == 2) ? b2 : b3;
          Mk[(size_t)row * NW + (o * 4 + g) * 4 + lane] = bs;
        }
      }
    }
  } else if (bid < 1088) {                // ---- Wo cast ----
    int i = (bid - 1024) * 1024 + tid * 4;
    float4 v = *(const float4*)(Wo + i);
    unsigned int p[2] = {pk2(v.x, v.y), pk2(v.z, v.w)};
    *(uint2*)(Wob + i) = *(const uint2*)p;
  } else {                                // ---- QKV gemm ----
    const int t = bid - 1088;             // 0..1535
    const int y = t >> 6, rb = t & 63;
    const int mat = y >> 3, ocb = (y & 7) * 32;
    const float* Wsrc = ((mat == 0) ? Wq : (mat == 1) ? Wk : Wv) + (size_t)ocb * DIN;

    #pragma unroll
    for (int it = 0; it < 8; ++it) {
      int f4 = it * 256 + tid;
      int oc = f4 >> 6, k4 = f4 & 63;
      float4 v = *(const float4*)(Wsrc + (size_t)oc * DIN + k4 * 4);
      unsigned int p[2] = {pk2(v.x, v.y), pk2(v.z, v.w)};
      *(uint2*)&Wl[oc][k4 * 4] = *(const uint2*)p;
    }
    __syncthreads();

    const int col = lane & 15, quad = lane >> 4;
    const int row0 = rb * 64 + w * 16;

    f32x4 acc[2];
    #pragma unroll
    for (int c = 0; c < 2; ++c) acc[c] = (f32x4){0.f, 0.f, 0.f, 0.f};

    #pragma unroll
    for (int kk = 0; kk < 8; ++kk) {
      const float* xp = x + (size_t)(row0 + col) * DIN + kk * 32 + quad * 8;
      float4 a0 = *(const float4*)xp, a1 = *(const float4*)(xp + 4);
      union { short8 s; unsigned int u[4]; } af;
      af.u[0] = pk2(a0.x, a0.y); af.u[1] = pk2(a0.z, a0.w);
      af.u[2] = pk2(a1.x, a1.y); af.u[3] = pk2(a1.z, a1.w);
      #pragma unroll
      for (int c = 0; c < 2; ++c) {
        short8 bw = *(const short8*)&Wl[c * 16 + col][kk * 32 + quad * 8];
        acc[c] = __builtin_amdgcn_mfma_f32_16x16x32_bf16(af.s, bw, acc[c], 0, 0, 0);
      }
    }
    const float scale = (mat == 0) ? QSCALE : 1.0f;
    #pragma unroll
    for (int c = 0; c < 2; ++c) {
      int oc = ocb + c * 16 + col, h = oc >> 5, dh = oc & 31;
      #pragma unroll
      for (int r = 0; r < 4; ++r) {
        int row = row0 + quad * 4 + r;
        int b = row >> 11, n = row & (NNN - 1);
        unsigned short val = f2bf(acc[c][r] * scale);
        if (mat == 2)       Vt[((size_t)(b * HH + h) * DHD + dh) * NNN + n] = val;
        else if (mat == 0)  Qb[((size_t)(b * HH + h) * NNN + n) * DHD + dh] = val;
        else                Kb[((size_t)(b * HH + h) * NNN + n) * DHD + dh] = val;
      }
    }
  }
}

// ---------------- K1: fused masked attention (chain-cut version) ----------------
// 1024 blocks x 512 thr (8 waves); wave w: keys [w*256,(w+1)*256) for 32 queries.
// Dual PV accumulators (half-length MFMA chain), tree-reduced lsum, explicit
// next-sub K/V prefetch, launch_bounds(512,4) for VGPR headroom.
__global__ __launch_bounds__(512, 4) void attn(
    const unsigned short* __restrict__ Qb, const unsigned short* __restrict__ Kb,
    const unsigned short* __restrict__ Vt, const unsigned long long* __restrict__ Mk,
    unsigned short* __restrict__ AOb) {
  __shared__ float OL[8][32][33];
  __shared__ float LL[8][32];
  const int tid = threadIdx.x;
  const int w = tid >> 6, lane = tid & 63;
  const int qi = lane & 31, hi = lane >> 5;
  const int bid = blockIdx.x;
  const int xcd = bid & 7, j = bid >> 3;
  const int bh = xcd * 2 + (j >> 6);       // 2 bh per XCD
  const int qt = j & 63;
  const int b = bh >> 3, h = bh & 7;
  const int q = qt * 32 + qi;
  const int k0 = w * 256;

  const unsigned short* qp = Qb + ((size_t)bh * NNN + q) * DHD + hi * 8;
  const short8 bq0 = *(const short8*)qp;
  const short8 bq1 = *(const short8*)(qp + 16);

  f32x16 accA, accB;
  #pragma unroll
  for (int i = 0; i < 16; ++i) { accA[i] = 0.f; accB[i] = 0.f; }
  float lsum = 0.f;

  // load 4 mask words, pre-shift by hi so later bit positions are compile-time
  const unsigned long long* mrow = Mk + ((size_t)b * NNN + q) * NW + w * 4;
  unsigned int mlo[4], mhi2[4];
  #pragma unroll
  for (int c = 0; c < 4; ++c) {
    unsigned long long mh = mrow[c] >> hi;
    mlo[c]  = (unsigned int)mh;
    mhi2[c] = (unsigned int)(mh >> 32);
  }

  const unsigned short* kbase = Kb + ((size_t)bh * NNN + k0 + qi) * DHD + hi * 8;  // qi = key
  const unsigned short* vbase = Vt + ((size_t)bh * DHD + qi) * NNN + k0 + hi * 8;  // qi = dh

  // prefetch sub 0
  short8 ak0 = *(const short8*)(kbase);
  short8 ak1 = *(const short8*)(kbase + 16);
  short8 av0 = *(const short8*)(vbase);
  short8 av1 = *(const short8*)(vbase + 16);

  #pragma unroll
  for (int sub = 0; sub < 8; ++sub) {
    const short8 cak0 = ak0, cak1 = ak1, cav0 = av0, cav1 = av1;
    if (sub < 7) {   // issue next-sub loads before the softmax chain
      const int kn = (sub + 1) * 32;
      ak0 = *(const short8*)(kbase + (size_t)kn * DHD);
      ak1 = *(const short8*)(kbase + (size_t)kn * DHD + 16);
      av0 = *(const short8*)(vbase + kn);
      av1 = *(const short8*)(vbase + kn + 16);
    }

    f32x16 z;
    #pragma unroll
    for (int i = 0; i < 16; ++i) z[i] = 0.f;
    // S^T: A=K(m=key), B=Q(n=query); C: query=lane&31, key=(reg&3)+8*(reg>>2)+4*hi
    f32x16 st = __builtin_amdgcn_mfma_f32_32x32x16_bf16(cak0, bq0, z, 0, 0, 0);
    st = __builtin_amdgcn_mfma_f32_32x32x16_bf16(cak1, bq1, st, 0, 0, 0);

    unsigned int pk[4][2];
    float gs[4];
    #pragma unroll
    for (int g = 0; g < 4; ++g) {
      float pv[4];
      #pragma unroll
      for (int r = 0; r < 4; ++r) {
        unsigned int mwd = (sub < 4) ? mlo[r] : mhi2[r];
        const int pos = (sub & 3) * 8 + g * 2;          // compile-time (full unroll)
        int msk = ((int)(mwd << (31 - pos))) >> 31;     // folds to bit-extract
        float e = EXP2(st[g * 4 + r]);
        pv[r] = __uint_as_float(__float_as_uint(e) & (unsigned int)msk);
      }
      gs[g] = (pv[0] + pv[1]) + (pv[2] + pv[3]);        // tree, depth 2
      pk[g][0] = pk2(pv[0], pv[1]);
      pk[g][1] = pk2(pv[2], pv[3]);
    }
    lsum += (gs[0] + gs[1]) + (gs[2] + gs[3]);          // one add into the carried chain

    // 8-shfl exchange: xg* = partner's pk[g][*]
    unsigned int x00 = __shfl_xor((int)pk[0][0], 32, 64), x01 = __shfl_xor((int)pk[0][1], 32, 64);
    unsigned int x10 = __shfl_xor((int)pk[1][0], 32, 64), x11 = __shfl_xor((int)pk[1][1], 32, 64);
    unsigned int x20 = __shfl_xor((int)pk[2][0], 32, 64), x21 = __shfl_xor((int)pk[2][1], 32, 64);
    unsigned int x30 = __shfl_xor((int)pk[3][0], 32, 64), x31 = __shfl_xor((int)pk[3][1], 32, 64);

    union { short8 s; unsigned int u[4]; } F1, F2;
    F1.u[0] = hi ? x10 : pk[0][0];
    F1.u[1] = hi ? x11 : pk[0][1];
    F1.u[2] = hi ? pk[1][0] : x00;
    F1.u[3] = hi ? pk[1][1] : x01;
    F2.u[0] = hi ? x30 : pk[2][0];
    F2.u[1] = hi ? x31 : pk[2][1];
    F2.u[2] = hi ? pk[3][0] : x20;
    F2.u[3] = hi ? pk[3][1] : x21;

    // O^T: split accumulation — keys [kb,kb+16) -> accA, [kb+16,kb+32) -> accB
    accA = __builtin_amdgcn_mfma_f32_32x32x16_bf16(cav0, F1.s, accA, 0, 0, 0);
    accB = __builtin_amdgcn_mfma_f32_32x32x16_bf16(cav1, F2.s, accB, 0, 0, 0);
  }

  lsum += __shfl_xor(lsum, 32, 64);   // hi halves cover disjoint keys

  #pragma unroll
  for (int g = 0; g < 4; ++g)
    #pragma unroll
    for (int r = 0; r < 4; ++r)
      OL[w][qi][g * 8 + hi * 4 + r] = accA[g * 4 + r] + accB[g * 4 + r];
  if (hi == 0) LL[w][qi] = lsum;
  __syncthreads();

  // 512 threads: 16 threads per query, 2 dh each
  const int ql = tid >> 4, c2 = (tid & 15) * 2;
  float l = 0.f, o0 = 0.f, o1 = 0.f;
  #pragma unroll
  for (int ww = 0; ww < 8; ++ww) {
    l  += LL[ww][ql];
    o0 += OL[ww][ql][c2];
    o1 += OL[ww][ql][c2 + 1];
  }
  float inv = 1.0f / l;
  unsigned int pr = pk2(o0 * inv, o1 * inv);
  *(unsigned int*)(AOb + ((size_t)(b * NNN + qt * 32 + ql)) * DIN + h * DHD + c2) = pr;
}

// ---------------- K2: output projection + bias via bf16 MFMA ----------------
__global__ __launch_bounds__(256) void out_proj(const unsigned short* __restrict__ AOb,
                                                const unsigned short* __restrict__ Wob,
                                                const float* __restrict__ bo,
                                                float* __restrict__ out) {
  const int tid = threadIdx.x;
  const int lane = tid & 63, col = lane & 15, quad = lane >> 4;
  const int task = blockIdx.x * 4 + (tid >> 6);    // 1024 tasks
  const int row0 = (task >> 2) * 16;
  const int ocb = (task & 3) * 64;

  f32x4 acc[4];
  #pragma unroll
  for (int c = 0; c < 4; ++c) acc[c] = (f32x4){0.f, 0.f, 0.f, 0.f};

  #pragma unroll
  for (int kk = 0; kk < 8; ++kk) {
    short8 af = *(const short8*)(AOb + (size_t)(row0 + col) * DIN + kk * 32 + quad * 8);
    #pragma unroll
    for (int c = 0; c < 4; ++c) {
      short8 bw = *(const short8*)(Wob + (size_t)(ocb + c * 16 + col) * DIN + kk * 32 + quad * 8);
      acc[c] = __builtin_amdgcn_mfma_f32_16x16x32_bf16(af, bw, acc[c], 0, 0, 0);
    }
  }
  #pragma unroll
  for (int c = 0; c < 4; ++c) {
    int oc = ocb + c * 16 + col;
    float bias = bo[oc];
    #pragma unroll
    for (int r = 0; r < 4; ++r)
      out[(size_t)(row0 + quad * 4 + r) * DIN + oc] = acc[c][r] + bias;
  }
}

extern "C" void kernel_launch(void* const* d_in, const int* in_sizes, int n_in,
                              void* d_out, int out_size, void* d_ws, size_t ws_size,
                              hipStream_t stream) {
  const float* x   = (const float*)d_in[0];
  const float* adj = (const float*)d_in[1];
  const float* Wq  = (const float*)d_in[2];
  const float* Wk  = (const float*)d_in[3];
  const float* Wv  = (const float*)d_in[4];
  const float* Wo  = (const float*)d_in[5];
  const float* bo  = (const float*)d_in[6];
  float* out = (float*)d_out;

  char* ws = (char*)d_ws;
  unsigned short* Qb  = (unsigned short*)(ws);                         // 2 MB
  unsigned short* Kb  = (unsigned short*)(ws + (2ull << 20));          // 2 MB
  unsigned short* Vt  = (unsigned short*)(ws + (4ull << 20));          // 2 MB
  unsigned long long* Mk = (unsigned long long*)(ws + (6ull << 20));   // 1 MB
  unsigned short* Wob = (unsigned short*)(ws + (7ull << 20));          // 128 KB
  unsigned short* AOb = (unsigned short*)(ws + (8ull << 20));          // 2 MB

  prep<<<dim3(2624), 256, 0, stream>>>(adj, Mk, x, Wq, Wk, Wv, Qb, Kb, Vt, Wo, Wob);
  attn<<<dim3(1024), 512, 0, stream>>>(Qb, Kb, Vt, Mk, AOb);
  out_proj<<<dim3(256), 256, 0, stream>>>(AOb, Wob, bo, out);
}